// Round 1
// baseline (2090.391 us; speedup 1.0000x reference)
//
#include <hip/hip_runtime.h>
#include <math.h>

#define N_NODES 100000
#define N_EDGES 1600000
#define IN_DIM  500
#define HID     64
#define OUT_DIM 40
#define BN_EPS  1e-5f

// ---------------- degree ----------------
__global__ void k_init_deg(float* deg) {
    int i = blockIdx.x * 256 + threadIdx.x;
    if (i < N_NODES) deg[i] = 1.0f;   // self-loop
}

__global__ void k_count_deg(const int* __restrict__ ei, float* deg) {
    int e = blockIdx.x * 256 + threadIdx.x;
    if (e < N_EDGES) atomicAdd(&deg[ei[N_EDGES + e]], 1.0f);
}

__global__ void k_rsqrt_deg(float* deg) {
    int i = blockIdx.x * 256 + threadIdx.x;
    if (i < N_NODES) deg[i] = rsqrtf(deg[i]);
}

// ---------------- dense: out[N,F] = x[N,K] @ W[K,F] ----------------
template <int K, int F>
__global__ void k_gemm(const float* __restrict__ x,
                       const float* __restrict__ W,
                       float* __restrict__ out) {
    long idx = (long)blockIdx.x * 256 + threadIdx.x;
    if (idx >= (long)N_NODES * F) return;
    int row = (int)(idx / F);
    int col = (int)(idx % F);
    const float* xr = x + (long)row * K;
    float acc = 0.0f;
#pragma unroll 4
    for (int k = 0; k < K; ++k) acc += xr[k] * W[k * F + col];
    out[idx] = acc;
}

// ---------------- agg init: self-loop term + bias ----------------
template <int F>
__global__ void k_self_init(const float* __restrict__ h,
                            const float* __restrict__ dis,
                            const float* __restrict__ b,
                            float* __restrict__ agg) {
    long idx = (long)blockIdx.x * 256 + threadIdx.x;
    if (idx >= (long)N_NODES * F) return;
    int row = (int)(idx / F);
    int col = (int)(idx % F);
    float d = dis[row];
    agg[idx] = h[idx] * d * d + b[col];
}

// ---------------- edge scatter: agg[dst] += h[src]*norm ----------------
template <int F>
__global__ void k_scatter(const float* __restrict__ h,
                          const int* __restrict__ ei,
                          const float* __restrict__ dis,
                          float* __restrict__ agg) {
    long idx = (long)blockIdx.x * 256 + threadIdx.x;
    if (idx >= (long)N_EDGES * F) return;
    int e = (int)(idx / F);
    int f = (int)(idx % F);
    int s = ei[e];
    int d = ei[N_EDGES + e];
    float norm = dis[s] * dis[d];
    atomicAdd(&agg[(long)d * F + f], h[(long)s * F + f] * norm);
}

// ---------------- BN (eval) + ReLU, in place ----------------
__global__ void k_bn_relu(float* __restrict__ a,
                          const float* __restrict__ g,
                          const float* __restrict__ be,
                          const float* __restrict__ m,
                          const float* __restrict__ v) {
    long idx = (long)blockIdx.x * 256 + threadIdx.x;
    if (idx >= (long)N_NODES * HID) return;
    int col = (int)(idx & (HID - 1));
    float x = a[idx];
    x = (x - m[col]) * rsqrtf(v[col] + BN_EPS) * g[col] + be[col];
    a[idx] = fmaxf(x, 0.0f);
}

// ---------------- row-wise log_softmax (one wave per row) ----------------
__global__ void k_log_softmax(const float* __restrict__ a,
                              float* __restrict__ out) {
    int wid  = (blockIdx.x * 256 + threadIdx.x) >> 6;
    int lane = threadIdx.x & 63;
    if (wid >= N_NODES) return;
    float val = (lane < OUT_DIM) ? a[(long)wid * OUT_DIM + lane] : -INFINITY;
    float mx = val;
#pragma unroll
    for (int o = 32; o > 0; o >>= 1) mx = fmaxf(mx, __shfl_xor(mx, o));
    float ex = (lane < OUT_DIM) ? expf(val - mx) : 0.0f;
    float s = ex;
#pragma unroll
    for (int o = 32; o > 0; o >>= 1) s += __shfl_xor(s, o);
    float ls = logf(s);
    if (lane < OUT_DIM) out[(long)wid * OUT_DIM + lane] = val - mx - ls;
}

static inline int cdiv(long a, int b) { return (int)((a + b - 1) / b); }

extern "C" void kernel_launch(void* const* d_in, const int* in_sizes, int n_in,
                              void* d_out, int out_size, void* d_ws, size_t ws_size,
                              hipStream_t stream) {
    const float* x   = (const float*)d_in[0];
    const int*   ei  = (const int*)d_in[1];
    const float* W1  = (const float*)d_in[2];
    const float* b1  = (const float*)d_in[3];
    const float* g1  = (const float*)d_in[4];
    const float* be1 = (const float*)d_in[5];
    const float* m1  = (const float*)d_in[6];
    const float* v1  = (const float*)d_in[7];
    const float* W2  = (const float*)d_in[8];
    const float* b2  = (const float*)d_in[9];
    const float* g2  = (const float*)d_in[10];
    const float* be2 = (const float*)d_in[11];
    const float* m2  = (const float*)d_in[12];
    const float* v2  = (const float*)d_in[13];
    const float* W3  = (const float*)d_in[14];
    const float* b3  = (const float*)d_in[15];
    float* out = (float*)d_out;

    float* ws   = (float*)d_ws;
    float* dis  = ws;                       // N floats (deg, then rsqrt in place)
    float* bufH = ws + 100096;              // N*64 floats
    float* bufA = bufH + (long)N_NODES * HID; // N*64 floats

    // degree + rsqrt
    k_init_deg<<<cdiv(N_NODES, 256), 256, 0, stream>>>(dis);
    k_count_deg<<<cdiv(N_EDGES, 256), 256, 0, stream>>>(ei, dis);
    k_rsqrt_deg<<<cdiv(N_NODES, 256), 256, 0, stream>>>(dis);

    // ---- layer 1: 500 -> 64 ----
    k_gemm<IN_DIM, HID><<<cdiv((long)N_NODES * HID, 256), 256, 0, stream>>>(x, W1, bufH);
    k_self_init<HID><<<cdiv((long)N_NODES * HID, 256), 256, 0, stream>>>(bufH, dis, b1, bufA);
    k_scatter<HID><<<cdiv((long)N_EDGES * HID, 256), 256, 0, stream>>>(bufH, ei, dis, bufA);
    k_bn_relu<<<cdiv((long)N_NODES * HID, 256), 256, 0, stream>>>(bufA, g1, be1, m1, v1);

    // ---- layer 2: 64 -> 64 ----
    k_gemm<HID, HID><<<cdiv((long)N_NODES * HID, 256), 256, 0, stream>>>(bufA, W2, bufH);
    k_self_init<HID><<<cdiv((long)N_NODES * HID, 256), 256, 0, stream>>>(bufH, dis, b2, bufA);
    k_scatter<HID><<<cdiv((long)N_EDGES * HID, 256), 256, 0, stream>>>(bufH, ei, dis, bufA);
    k_bn_relu<<<cdiv((long)N_NODES * HID, 256), 256, 0, stream>>>(bufA, g2, be2, m2, v2);

    // ---- layer 3: 64 -> 40 ----
    k_gemm<HID, OUT_DIM><<<cdiv((long)N_NODES * OUT_DIM, 256), 256, 0, stream>>>(bufA, W3, bufH);
    k_self_init<OUT_DIM><<<cdiv((long)N_NODES * OUT_DIM, 256), 256, 0, stream>>>(bufH, dis, b3, bufA);
    k_scatter<OUT_DIM><<<cdiv((long)N_EDGES * OUT_DIM, 256), 256, 0, stream>>>(bufH, ei, dis, bufA);

    // log_softmax -> out
    k_log_softmax<<<cdiv((long)N_NODES * 64, 256), 256, 0, stream>>>(bufA, out);
}

// Round 2
// 1333.442 us; speedup vs baseline: 1.5677x; 1.5677x over previous
//
#include <hip/hip_runtime.h>
#include <math.h>

#define N_NODES 100000
#define N_EDGES 1600000
#define IN_DIM  500
#define HID     64
#define OUT_DIM 40
#define BN_EPS  1e-5f

// ---------------- degree ----------------
__global__ void k_init_deg(float* deg) {
    int i = blockIdx.x * 256 + threadIdx.x;
    if (i < N_NODES) deg[i] = 1.0f;   // self-loop
}

__global__ void k_count_deg(const int* __restrict__ ei, float* deg) {
    int e = blockIdx.x * 256 + threadIdx.x;
    if (e < N_EDGES) atomicAdd(&deg[ei[N_EDGES + e]], 1.0f);
}

__global__ void k_rsqrt_deg(float* deg) {
    int i = blockIdx.x * 256 + threadIdx.x;
    if (i < N_NODES) deg[i] = rsqrtf(deg[i]);
}

// ---------------- tiled GEMM + fused self-loop epilogue ----------------
// h[N,F] = x[N,K] @ W[K,F];  agg[N,F] = h*dis^2 + b
// BM=64 rows, BN=64 cols (F<=64, zero-padded), BK=64, 256 threads, 4x4 micro-tile.
template <int K, int F>
__global__ __launch_bounds__(256) void k_gemm_fused(
        const float* __restrict__ x, const float* __restrict__ W,
        const float* __restrict__ bias, const float* __restrict__ dis,
        float* __restrict__ h, float* __restrict__ agg) {
    constexpr int BK = 64;
    __shared__ float xs[64][BK + 4];   // stride 68 floats: 16B-aligned rows, bank-safe
    __shared__ float ws[BK][64 + 4];

    const int tid  = threadIdx.x;
    const int cn   = (tid & 15) * 4;   // col within tile
    const int rm   = (tid >> 4) * 4;   // row within tile
    const int brow = blockIdx.x * 64;

    float acc[4][4] = {};

    for (int k0 = 0; k0 < K; k0 += BK) {
        const int krem = K - k0;   // may be < BK on tail (e.g. 500 -> 52)

        // stage x tile: 64 rows x BK cols (zero-pad k-tail)
#pragma unroll
        for (int rep = 0; rep < 4; ++rep) {
            int row  = rep * 16 + (tid >> 4);
            int colv = (tid & 15) * 4;
            int grow = brow + row;
            float4 val = make_float4(0.f, 0.f, 0.f, 0.f);
            if (grow < N_NODES) {
                if (colv + 4 <= krem) {
                    val = *reinterpret_cast<const float4*>(x + (long)grow * K + k0 + colv);
                } else {
                    float t0 = (colv + 0 < krem) ? x[(long)grow * K + k0 + colv + 0] : 0.f;
                    float t1 = (colv + 1 < krem) ? x[(long)grow * K + k0 + colv + 1] : 0.f;
                    float t2 = (colv + 2 < krem) ? x[(long)grow * K + k0 + colv + 2] : 0.f;
                    float t3 = (colv + 3 < krem) ? x[(long)grow * K + k0 + colv + 3] : 0.f;
                    val = make_float4(t0, t1, t2, t3);
                }
            }
            *reinterpret_cast<float4*>(&xs[row][colv]) = val;
        }

        // stage W tile: BK rows x F cols (zero-pad k-tail and cols F..63)
#pragma unroll
        for (int rep = 0; rep < 4; ++rep) {
            int row  = rep * 16 + (tid >> 4);
            int colv = (tid & 15) * 4;
            float4 val = make_float4(0.f, 0.f, 0.f, 0.f);
            if (row < krem) {
                if (F == 64) {
                    val = *reinterpret_cast<const float4*>(W + (long)(k0 + row) * F + colv);
                } else {
                    float t0 = (colv + 0 < F) ? W[(long)(k0 + row) * F + colv + 0] : 0.f;
                    float t1 = (colv + 1 < F) ? W[(long)(k0 + row) * F + colv + 1] : 0.f;
                    float t2 = (colv + 2 < F) ? W[(long)(k0 + row) * F + colv + 2] : 0.f;
                    float t3 = (colv + 3 < F) ? W[(long)(k0 + row) * F + colv + 3] : 0.f;
                    val = make_float4(t0, t1, t2, t3);
                }
            }
            *reinterpret_cast<float4*>(&ws[row][colv]) = val;
        }

        __syncthreads();

#pragma unroll 16
        for (int kk = 0; kk < BK; ++kk) {
            float4 bv = *reinterpret_cast<const float4*>(&ws[kk][cn]);
            float bb[4] = {bv.x, bv.y, bv.z, bv.w};
            float av[4];
#pragma unroll
            for (int i = 0; i < 4; ++i) av[i] = xs[rm + i][kk];
#pragma unroll
            for (int i = 0; i < 4; ++i)
#pragma unroll
                for (int j = 0; j < 4; ++j)
                    acc[i][j] += av[i] * bb[j];
        }

        __syncthreads();
    }

    // epilogue: h = acc ; agg = acc*dis^2 + bias
    if (cn < F) {
        float4 bvb = *reinterpret_cast<const float4*>(bias + cn);
#pragma unroll
        for (int i = 0; i < 4; ++i) {
            int grow = brow + rm + i;
            if (grow >= N_NODES) continue;
            float d  = dis[grow];
            float d2 = d * d;
            float4 hv = make_float4(acc[i][0], acc[i][1], acc[i][2], acc[i][3]);
            float4 av = make_float4(hv.x * d2 + bvb.x, hv.y * d2 + bvb.y,
                                    hv.z * d2 + bvb.z, hv.w * d2 + bvb.w);
            *reinterpret_cast<float4*>(h   + (long)grow * F + cn) = hv;
            *reinterpret_cast<float4*>(agg + (long)grow * F + cn) = av;
        }
    }
}

// ---------------- edge scatter: agg[dst] += h[src]*norm ----------------
template <int F>
__global__ void k_scatter(const float* __restrict__ h,
                          const int* __restrict__ ei,
                          const float* __restrict__ dis,
                          float* __restrict__ agg) {
    long idx = (long)blockIdx.x * 256 + threadIdx.x;
    if (idx >= (long)N_EDGES * F) return;
    int e = (int)(idx / F);
    int f = (int)(idx % F);
    int s = ei[e];
    int d = ei[N_EDGES + e];
    float norm = dis[s] * dis[d];
    atomicAdd(&agg[(long)d * F + f], h[(long)s * F + f] * norm);
}

// ---------------- BN (eval) + ReLU, in place ----------------
__global__ void k_bn_relu(float* __restrict__ a,
                          const float* __restrict__ g,
                          const float* __restrict__ be,
                          const float* __restrict__ m,
                          const float* __restrict__ v) {
    long idx = (long)blockIdx.x * 256 + threadIdx.x;
    if (idx >= (long)N_NODES * HID) return;
    int col = (int)(idx & (HID - 1));
    float x = a[idx];
    x = (x - m[col]) * rsqrtf(v[col] + BN_EPS) * g[col] + be[col];
    a[idx] = fmaxf(x, 0.0f);
}

// ---------------- row-wise log_softmax (one wave per row) ----------------
__global__ void k_log_softmax(const float* __restrict__ a,
                              float* __restrict__ out) {
    int wid  = (blockIdx.x * 256 + threadIdx.x) >> 6;
    int lane = threadIdx.x & 63;
    if (wid >= N_NODES) return;
    float val = (lane < OUT_DIM) ? a[(long)wid * OUT_DIM + lane] : -INFINITY;
    float mx = val;
#pragma unroll
    for (int o = 32; o > 0; o >>= 1) mx = fmaxf(mx, __shfl_xor(mx, o));
    float ex = (lane < OUT_DIM) ? expf(val - mx) : 0.0f;
    float s = ex;
#pragma unroll
    for (int o = 32; o > 0; o >>= 1) s += __shfl_xor(s, o);
    float ls = logf(s);
    if (lane < OUT_DIM) out[(long)wid * OUT_DIM + lane] = val - mx - ls;
}

static inline int cdiv(long a, int b) { return (int)((a + b - 1) / b); }

extern "C" void kernel_launch(void* const* d_in, const int* in_sizes, int n_in,
                              void* d_out, int out_size, void* d_ws, size_t ws_size,
                              hipStream_t stream) {
    const float* x   = (const float*)d_in[0];
    const int*   ei  = (const int*)d_in[1];
    const float* W1  = (const float*)d_in[2];
    const float* b1  = (const float*)d_in[3];
    const float* g1  = (const float*)d_in[4];
    const float* be1 = (const float*)d_in[5];
    const float* m1  = (const float*)d_in[6];
    const float* v1  = (const float*)d_in[7];
    const float* W2  = (const float*)d_in[8];
    const float* b2  = (const float*)d_in[9];
    const float* g2  = (const float*)d_in[10];
    const float* be2 = (const float*)d_in[11];
    const float* m2  = (const float*)d_in[12];
    const float* v2  = (const float*)d_in[13];
    const float* W3  = (const float*)d_in[14];
    const float* b3  = (const float*)d_in[15];
    float* out = (float*)d_out;

    float* ws   = (float*)d_ws;
    float* dis  = ws;                         // N floats
    float* bufH = ws + 100096;                // N*64
    float* bufA = bufH + (long)N_NODES * HID; // N*64

    // degree + rsqrt
    k_init_deg<<<cdiv(N_NODES, 256), 256, 0, stream>>>(dis);
    k_count_deg<<<cdiv(N_EDGES, 256), 256, 0, stream>>>(ei, dis);
    k_rsqrt_deg<<<cdiv(N_NODES, 256), 256, 0, stream>>>(dis);

    const int gemm_grid = cdiv(N_NODES, 64);

    // ---- layer 1: 500 -> 64 ----
    k_gemm_fused<IN_DIM, HID><<<gemm_grid, 256, 0, stream>>>(x, W1, b1, dis, bufH, bufA);
    k_scatter<HID><<<cdiv((long)N_EDGES * HID, 256), 256, 0, stream>>>(bufH, ei, dis, bufA);
    k_bn_relu<<<cdiv((long)N_NODES * HID, 256), 256, 0, stream>>>(bufA, g1, be1, m1, v1);

    // ---- layer 2: 64 -> 64 ----
    k_gemm_fused<HID, HID><<<gemm_grid, 256, 0, stream>>>(bufA, W2, b2, dis, bufH, bufA);
    k_scatter<HID><<<cdiv((long)N_EDGES * HID, 256), 256, 0, stream>>>(bufH, ei, dis, bufA);
    k_bn_relu<<<cdiv((long)N_NODES * HID, 256), 256, 0, stream>>>(bufA, g2, be2, m2, v2);

    // ---- layer 3: 64 -> 40 ----
    k_gemm_fused<HID, OUT_DIM><<<gemm_grid, 256, 0, stream>>>(bufA, W3, b3, dis, bufH, bufA);
    k_scatter<OUT_DIM><<<cdiv((long)N_EDGES * OUT_DIM, 256), 256, 0, stream>>>(bufH, ei, dis, bufA);

    // log_softmax -> out
    k_log_softmax<<<cdiv((long)N_NODES * 64, 256), 256, 0, stream>>>(bufA, out);
}

// Round 3
// 574.454 us; speedup vs baseline: 3.6389x; 2.3212x over previous
//
#include <hip/hip_runtime.h>
#include <math.h>

#define N_NODES 100000
#define N_EDGES 1600000
#define IN_DIM  500
#define HID     64
#define OUT_DIM 40
#define BN_EPS  1e-5f
#define SCAN_NB 98          // ceil(100000 / 1024)

static inline int cdiv(long a, int b) { return (int)((a + b - 1) / b); }

// ---------------- zero int scratch ----------------
__global__ void k_zero2(int* a, int* b) {
    int i = blockIdx.x * 256 + threadIdx.x;
    if (i < N_NODES) { a[i] = 0; b[i] = 0; }
}

// ---------------- integer in-degree ----------------
__global__ void k_count_deg(const int* __restrict__ ei, int* degi) {
    int e = blockIdx.x * 256 + threadIdx.x;
    if (e < N_EDGES) atomicAdd(&degi[ei[N_EDGES + e]], 1);
}

__global__ void k_dis(const int* __restrict__ degi, float* dis) {
    int i = blockIdx.x * 256 + threadIdx.x;
    if (i < N_NODES) dis[i] = rsqrtf((float)degi[i] + 1.0f);
}

// ---------------- exclusive scan (3 kernels) ----------------
__global__ void k_scan1(const int* __restrict__ degi, int* __restrict__ rowptr,
                        int* __restrict__ blocksum) {
    __shared__ int sd[256];
    int tid = threadIdx.x;
    int base = blockIdx.x * 1024 + tid * 4;
    int v0 = (base + 0 < N_NODES) ? degi[base + 0] : 0;
    int v1 = (base + 1 < N_NODES) ? degi[base + 1] : 0;
    int v2 = (base + 2 < N_NODES) ? degi[base + 2] : 0;
    int v3 = (base + 3 < N_NODES) ? degi[base + 3] : 0;
    int s = v0 + v1 + v2 + v3;
    sd[tid] = s;
    __syncthreads();
    for (int off = 1; off < 256; off <<= 1) {
        int t = (tid >= off) ? sd[tid - off] : 0;
        __syncthreads();
        sd[tid] += t;
        __syncthreads();
    }
    int excl = sd[tid] - s;
    if (base + 0 < N_NODES) rowptr[base + 0] = excl;
    if (base + 1 < N_NODES) rowptr[base + 1] = excl + v0;
    if (base + 2 < N_NODES) rowptr[base + 2] = excl + v0 + v1;
    if (base + 3 < N_NODES) rowptr[base + 3] = excl + v0 + v1 + v2;
    if (tid == 255) blocksum[blockIdx.x] = sd[255];
}

__global__ void k_scan2(int* __restrict__ blocksum, int* __restrict__ blockbase) {
    __shared__ int sd[128];
    int tid = threadIdx.x;
    int v = (tid < SCAN_NB) ? blocksum[tid] : 0;
    sd[tid] = v;
    __syncthreads();
    for (int off = 1; off < 128; off <<= 1) {
        int t = (tid >= off) ? sd[tid - off] : 0;
        __syncthreads();
        sd[tid] += t;
        __syncthreads();
    }
    if (tid < SCAN_NB) blockbase[tid] = sd[tid] - v;
}

__global__ void k_scan3(int* __restrict__ rowptr, const int* __restrict__ blockbase) {
    int add = blockbase[blockIdx.x];
    int base = blockIdx.x * 1024 + threadIdx.x * 4;
#pragma unroll
    for (int i = 0; i < 4; ++i)
        if (base + i < N_NODES) rowptr[base + i] += add;
}

// ---------------- CSR permute: group edges by dst ----------------
__global__ void k_permute(const int* __restrict__ ei, const int* __restrict__ rowptr,
                          int* __restrict__ cursor, const float* __restrict__ dis,
                          int* __restrict__ col, float* __restrict__ valn) {
    int e = blockIdx.x * 256 + threadIdx.x;
    if (e >= N_EDGES) return;
    int s = ei[e];
    int d = ei[N_EDGES + e];
    int pos = rowptr[d] + atomicAdd(&cursor[d], 1);
    col[pos]  = s;
    valn[pos] = dis[s] * dis[d];
}

// ---------------- tiled GEMM: h[N,F] = x[N,K] @ W[K,F] ----------------
template <int K, int F>
__global__ __launch_bounds__(256) void k_gemm(
        const float* __restrict__ x, const float* __restrict__ W,
        float* __restrict__ h) {
    constexpr int BK = 64;
    __shared__ float xs[64][BK + 4];
    __shared__ float ws[BK][64 + 4];

    const int tid  = threadIdx.x;
    const int cn   = (tid & 15) * 4;
    const int rm   = (tid >> 4) * 4;
    const int brow = blockIdx.x * 64;

    float acc[4][4] = {};

    for (int k0 = 0; k0 < K; k0 += BK) {
        const int krem = K - k0;

#pragma unroll
        for (int rep = 0; rep < 4; ++rep) {
            int row  = rep * 16 + (tid >> 4);
            int colv = (tid & 15) * 4;
            int grow = brow + row;
            float4 val = make_float4(0.f, 0.f, 0.f, 0.f);
            if (grow < N_NODES) {
                if (colv + 4 <= krem) {
                    val = *reinterpret_cast<const float4*>(x + (long)grow * K + k0 + colv);
                } else {
                    float t0 = (colv + 0 < krem) ? x[(long)grow * K + k0 + colv + 0] : 0.f;
                    float t1 = (colv + 1 < krem) ? x[(long)grow * K + k0 + colv + 1] : 0.f;
                    float t2 = (colv + 2 < krem) ? x[(long)grow * K + k0 + colv + 2] : 0.f;
                    float t3 = (colv + 3 < krem) ? x[(long)grow * K + k0 + colv + 3] : 0.f;
                    val = make_float4(t0, t1, t2, t3);
                }
            }
            *reinterpret_cast<float4*>(&xs[row][colv]) = val;
        }

#pragma unroll
        for (int rep = 0; rep < 4; ++rep) {
            int row  = rep * 16 + (tid >> 4);
            int colv = (tid & 15) * 4;
            float4 val = make_float4(0.f, 0.f, 0.f, 0.f);
            if (row < krem) {
                if (F == 64) {
                    val = *reinterpret_cast<const float4*>(W + (long)(k0 + row) * F + colv);
                } else {
                    float t0 = (colv + 0 < F) ? W[(long)(k0 + row) * F + colv + 0] : 0.f;
                    float t1 = (colv + 1 < F) ? W[(long)(k0 + row) * F + colv + 1] : 0.f;
                    float t2 = (colv + 2 < F) ? W[(long)(k0 + row) * F + colv + 2] : 0.f;
                    float t3 = (colv + 3 < F) ? W[(long)(k0 + row) * F + colv + 3] : 0.f;
                    val = make_float4(t0, t1, t2, t3);
                }
            }
            *reinterpret_cast<float4*>(&ws[row][colv]) = val;
        }

        __syncthreads();

#pragma unroll 16
        for (int kk = 0; kk < BK; ++kk) {
            float4 bv = *reinterpret_cast<const float4*>(&ws[kk][cn]);
            float bb[4] = {bv.x, bv.y, bv.z, bv.w};
            float av[4];
#pragma unroll
            for (int i = 0; i < 4; ++i) av[i] = xs[rm + i][kk];
#pragma unroll
            for (int i = 0; i < 4; ++i)
#pragma unroll
                for (int j = 0; j < 4; ++j)
                    acc[i][j] += av[i] * bb[j];
        }

        __syncthreads();
    }

    if (cn < F) {
#pragma unroll
        for (int i = 0; i < 4; ++i) {
            int grow = brow + rm + i;
            if (grow >= N_NODES) continue;
            *reinterpret_cast<float4*>(h + (long)grow * F + cn) =
                make_float4(acc[i][0], acc[i][1], acc[i][2], acc[i][3]);
        }
    }
}

// ---------------- pull aggregation + bias + BN + ReLU ----------------
// one wave per node; lane = feature column
template <int F>
__global__ __launch_bounds__(256) void k_agg_bn_relu(
        const float* __restrict__ h, const int* __restrict__ rowptr,
        const int* __restrict__ degi, const int* __restrict__ col,
        const float* __restrict__ valn, const float* __restrict__ dis,
        const float* __restrict__ bias, const float* __restrict__ g,
        const float* __restrict__ be, const float* __restrict__ m,
        const float* __restrict__ v, float* __restrict__ out) {
    int wid  = (blockIdx.x * 256 + threadIdx.x) >> 6;
    int lane = threadIdx.x & 63;
    if (wid >= N_NODES) return;

    int start = rowptr[wid];
    int cnt   = degi[wid];

    float acc = 0.0f;
    if (lane < F) {
        float d = dis[wid];
        acc = h[(long)wid * F + lane] * d * d + bias[lane];
    }

    int j = 0;
    for (; j + 4 <= cnt; j += 4) {
        int   s0 = col[start + j + 0], s1 = col[start + j + 1];
        int   s2 = col[start + j + 2], s3 = col[start + j + 3];
        float w0 = valn[start + j + 0], w1 = valn[start + j + 1];
        float w2 = valn[start + j + 2], w3 = valn[start + j + 3];
        if (lane < F) {
            float h0 = h[(long)s0 * F + lane];
            float h1 = h[(long)s1 * F + lane];
            float h2 = h[(long)s2 * F + lane];
            float h3 = h[(long)s3 * F + lane];
            acc += h0 * w0; acc += h1 * w1; acc += h2 * w2; acc += h3 * w3;
        }
    }
    for (; j < cnt; ++j) {
        int   s = col[start + j];
        float w = valn[start + j];
        if (lane < F) acc += h[(long)s * F + lane] * w;
    }

    if (lane < F) {
        float xv = (acc - m[lane]) * rsqrtf(v[lane] + BN_EPS) * g[lane] + be[lane];
        out[(long)wid * F + lane] = fmaxf(xv, 0.0f);
    }
}

// ---------------- pull aggregation + bias + log_softmax (layer 3) ----------------
template <int F>
__global__ __launch_bounds__(256) void k_agg_lsm(
        const float* __restrict__ h, const int* __restrict__ rowptr,
        const int* __restrict__ degi, const int* __restrict__ col,
        const float* __restrict__ valn, const float* __restrict__ dis,
        const float* __restrict__ bias, float* __restrict__ out) {
    int wid  = (blockIdx.x * 256 + threadIdx.x) >> 6;
    int lane = threadIdx.x & 63;
    if (wid >= N_NODES) return;

    int start = rowptr[wid];
    int cnt   = degi[wid];

    float acc = 0.0f;
    if (lane < F) {
        float d = dis[wid];
        acc = h[(long)wid * F + lane] * d * d + bias[lane];
    }

    int j = 0;
    for (; j + 4 <= cnt; j += 4) {
        int   s0 = col[start + j + 0], s1 = col[start + j + 1];
        int   s2 = col[start + j + 2], s3 = col[start + j + 3];
        float w0 = valn[start + j + 0], w1 = valn[start + j + 1];
        float w2 = valn[start + j + 2], w3 = valn[start + j + 3];
        if (lane < F) {
            float h0 = h[(long)s0 * F + lane];
            float h1 = h[(long)s1 * F + lane];
            float h2 = h[(long)s2 * F + lane];
            float h3 = h[(long)s3 * F + lane];
            acc += h0 * w0; acc += h1 * w1; acc += h2 * w2; acc += h3 * w3;
        }
    }
    for (; j < cnt; ++j) {
        int   s = col[start + j];
        float w = valn[start + j];
        if (lane < F) acc += h[(long)s * F + lane] * w;
    }

    float valf = (lane < F) ? acc : -INFINITY;
    float mx = valf;
#pragma unroll
    for (int o = 32; o > 0; o >>= 1) mx = fmaxf(mx, __shfl_xor(mx, o));
    float ex = (lane < F) ? expf(valf - mx) : 0.0f;
    float sm = ex;
#pragma unroll
    for (int o = 32; o > 0; o >>= 1) sm += __shfl_xor(sm, o);
    float ls = logf(sm);
    if (lane < F) out[(long)wid * F + lane] = valf - mx - ls;
}

extern "C" void kernel_launch(void* const* d_in, const int* in_sizes, int n_in,
                              void* d_out, int out_size, void* d_ws, size_t ws_size,
                              hipStream_t stream) {
    const float* x   = (const float*)d_in[0];
    const int*   ei  = (const int*)d_in[1];
    const float* W1  = (const float*)d_in[2];
    const float* b1  = (const float*)d_in[3];
    const float* g1  = (const float*)d_in[4];
    const float* be1 = (const float*)d_in[5];
    const float* m1  = (const float*)d_in[6];
    const float* v1  = (const float*)d_in[7];
    const float* W2  = (const float*)d_in[8];
    const float* b2  = (const float*)d_in[9];
    const float* g2  = (const float*)d_in[10];
    const float* be2 = (const float*)d_in[11];
    const float* m2  = (const float*)d_in[12];
    const float* v2  = (const float*)d_in[13];
    const float* W3  = (const float*)d_in[14];
    const float* b3  = (const float*)d_in[15];
    float* out = (float*)d_out;

    // workspace layout (all 16B-aligned)
    float* ws        = (float*)d_ws;
    float* dis       = ws;                            // 100096
    int*   degi      = (int*)(ws + 100096);           // 100096
    int*   cursor    = degi + 100096;                 // 100096
    int*   rowptr    = cursor + 100096;               // 100096
    int*   blocksum  = rowptr + 100096;               // 128
    int*   blockbase = blocksum + 128;                // 128
    int*   col       = blockbase + 128;               // 1.6M
    float* valn      = (float*)(col + N_EDGES);       // 1.6M
    float* bufH      = valn + N_EDGES;                // 6.4M
    float* bufA      = bufH + (long)N_NODES * HID;    // 6.4M

    // ---- CSR build ----
    k_zero2<<<cdiv(N_NODES, 256), 256, 0, stream>>>(degi, cursor);
    k_count_deg<<<cdiv(N_EDGES, 256), 256, 0, stream>>>(ei, degi);
    k_dis<<<cdiv(N_NODES, 256), 256, 0, stream>>>(degi, dis);
    k_scan1<<<SCAN_NB, 256, 0, stream>>>(degi, rowptr, blocksum);
    k_scan2<<<1, 128, 0, stream>>>(blocksum, blockbase);
    k_scan3<<<SCAN_NB, 256, 0, stream>>>(rowptr, blockbase);
    k_permute<<<cdiv(N_EDGES, 256), 256, 0, stream>>>(ei, rowptr, cursor, dis, col, valn);

    const int gemm_grid = cdiv(N_NODES, 64);
    const int agg_grid  = cdiv((long)N_NODES * 64, 256);

    // ---- layer 1: 500 -> 64 ----
    k_gemm<IN_DIM, HID><<<gemm_grid, 256, 0, stream>>>(x, W1, bufH);
    k_agg_bn_relu<HID><<<agg_grid, 256, 0, stream>>>(bufH, rowptr, degi, col, valn,
                                                     dis, b1, g1, be1, m1, v1, bufA);

    // ---- layer 2: 64 -> 64 ----
    k_gemm<HID, HID><<<gemm_grid, 256, 0, stream>>>(bufA, W2, bufH);
    k_agg_bn_relu<HID><<<agg_grid, 256, 0, stream>>>(bufH, rowptr, degi, col, valn,
                                                     dis, b2, g2, be2, m2, v2, bufA);

    // ---- layer 3: 64 -> 40 ----
    k_gemm<HID, OUT_DIM><<<gemm_grid, 256, 0, stream>>>(bufA, W3, bufH);
    k_agg_lsm<OUT_DIM><<<agg_grid, 256, 0, stream>>>(bufH, rowptr, degi, col, valn,
                                                     dis, b3, out);
}

// Round 4
// 555.631 us; speedup vs baseline: 3.7622x; 1.0339x over previous
//
#include <hip/hip_runtime.h>
#include <math.h>

#define N_NODES 100000
#define N_EDGES 1600000
#define IN_DIM  500
#define HID     64
#define OUT_DIM 40
#define BN_EPS  1e-5f
#define SCAN_NB 98          // ceil(100000 / 1024)

static inline int cdiv(long a, int b) { return (int)((a + b - 1) / b); }

// ---------------- zero int scratch ----------------
__global__ void k_zero2(int* a, int* b) {
    int i = blockIdx.x * 256 + threadIdx.x;
    if (i < N_NODES) { a[i] = 0; b[i] = 0; }
}

// ---------------- integer in-degree ----------------
__global__ void k_count_deg(const int* __restrict__ ei, int* degi) {
    int e = blockIdx.x * 256 + threadIdx.x;
    if (e < N_EDGES) atomicAdd(&degi[ei[N_EDGES + e]], 1);
}

__global__ void k_dis(const int* __restrict__ degi, float* dis) {
    int i = blockIdx.x * 256 + threadIdx.x;
    if (i < N_NODES) dis[i] = rsqrtf((float)degi[i] + 1.0f);
}

// ---------------- exclusive scan (3 kernels) ----------------
__global__ void k_scan1(const int* __restrict__ degi, int* __restrict__ rowptr,
                        int* __restrict__ blocksum) {
    __shared__ int sd[256];
    int tid = threadIdx.x;
    int base = blockIdx.x * 1024 + tid * 4;
    int v0 = (base + 0 < N_NODES) ? degi[base + 0] : 0;
    int v1 = (base + 1 < N_NODES) ? degi[base + 1] : 0;
    int v2 = (base + 2 < N_NODES) ? degi[base + 2] : 0;
    int v3 = (base + 3 < N_NODES) ? degi[base + 3] : 0;
    int s = v0 + v1 + v2 + v3;
    sd[tid] = s;
    __syncthreads();
    for (int off = 1; off < 256; off <<= 1) {
        int t = (tid >= off) ? sd[tid - off] : 0;
        __syncthreads();
        sd[tid] += t;
        __syncthreads();
    }
    int excl = sd[tid] - s;
    if (base + 0 < N_NODES) rowptr[base + 0] = excl;
    if (base + 1 < N_NODES) rowptr[base + 1] = excl + v0;
    if (base + 2 < N_NODES) rowptr[base + 2] = excl + v0 + v1;
    if (base + 3 < N_NODES) rowptr[base + 3] = excl + v0 + v1 + v2;
    if (tid == 255) blocksum[blockIdx.x] = sd[255];
}

__global__ void k_scan2(int* __restrict__ blocksum, int* __restrict__ blockbase) {
    __shared__ int sd[128];
    int tid = threadIdx.x;
    int v = (tid < SCAN_NB) ? blocksum[tid] : 0;
    sd[tid] = v;
    __syncthreads();
    for (int off = 1; off < 128; off <<= 1) {
        int t = (tid >= off) ? sd[tid - off] : 0;
        __syncthreads();
        sd[tid] += t;
        __syncthreads();
    }
    if (tid < SCAN_NB) blockbase[tid] = sd[tid] - v;
}

__global__ void k_scan3(int* __restrict__ rowptr, const int* __restrict__ blockbase) {
    int add = blockbase[blockIdx.x];
    int base = blockIdx.x * 1024 + threadIdx.x * 4;
#pragma unroll
    for (int i = 0; i < 4; ++i)
        if (base + i < N_NODES) rowptr[base + i] += add;
}

// ---------------- CSR permute: group edges by dst ----------------
__global__ void k_permute(const int* __restrict__ ei, const int* __restrict__ rowptr,
                          int* __restrict__ cursor, const float* __restrict__ dis,
                          int* __restrict__ col, float* __restrict__ valn) {
    int e = blockIdx.x * 256 + threadIdx.x;
    if (e >= N_EDGES) return;
    int s = ei[e];
    int d = ei[N_EDGES + e];
    int pos = rowptr[d] + atomicAdd(&cursor[d], 1);
    col[pos]  = s;
    valn[pos] = dis[s] * dis[d];
}

// ---------------- tiled GEMM: h[N,F] = x[N,K] @ W[K,F] ----------------
// BM=128, BN=64 (F<=64 zero-padded), BK=32, 256 threads, 8x4 micro-tile.
// A staged TRANSPOSED in LDS so the 8 A-values per kk are 2x ds_read_b128.
template <int K, int F>
__global__ __launch_bounds__(256) void k_gemm(
        const float* __restrict__ x, const float* __restrict__ W,
        float* __restrict__ h) {
    constexpr int BM = 128, BN = 64, BK = 32;
    __shared__ float xst[BK][BM + 4];   // transposed: [k][row], stride 132 (16B-mult)
    __shared__ float ws[BK][BN + 4];    // [k][col], stride 68

    const int tid = threadIdx.x;
    const int tx  = tid & 15;           // 0..15 -> cn = 4*tx
    const int ty  = tid >> 4;           // 0..15 -> rm = 8*ty
    const int cn  = tx * 4;
    const int rm  = ty * 8;
    const int brow = blockIdx.x * BM;

    // staging maps
    const int aq = tid & 7;             // col-quad 0..7 (cols 4*aq)
    const int ar = tid >> 3;            // row 0..31 (+32 per rep)
    const int bq = tid & 15;            // col-quad 0..15
    const int br = tid >> 4;            // row 0..15 (+16 per rep)

    float acc[8][4] = {};

    for (int k0 = 0; k0 < K; k0 += BK) {
        const int krem = K - k0;        // may be < BK on tail (500 -> 20)

        // ---- stage A transposed: rows brow..brow+127, cols k0..k0+31 ----
#pragma unroll
        for (int rep = 0; rep < 4; ++rep) {
            int row  = ar + rep * 32;
            int grow = brow + row;
            int c    = aq * 4;
            float4 val = make_float4(0.f, 0.f, 0.f, 0.f);
            if (grow < N_NODES) {
                if (c + 4 <= krem) {
                    val = *reinterpret_cast<const float4*>(x + (long)grow * K + k0 + c);
                } else {
                    float t0 = (c + 0 < krem) ? x[(long)grow * K + k0 + c + 0] : 0.f;
                    float t1 = (c + 1 < krem) ? x[(long)grow * K + k0 + c + 1] : 0.f;
                    float t2 = (c + 2 < krem) ? x[(long)grow * K + k0 + c + 2] : 0.f;
                    float t3 = (c + 3 < krem) ? x[(long)grow * K + k0 + c + 3] : 0.f;
                    val = make_float4(t0, t1, t2, t3);
                }
            }
            xst[c + 0][row] = val.x;
            xst[c + 1][row] = val.y;
            xst[c + 2][row] = val.z;
            xst[c + 3][row] = val.w;
        }

        // ---- stage B: rows k0..k0+31 of W, cols 0..63 (zero-pad) ----
#pragma unroll
        for (int rep = 0; rep < 2; ++rep) {
            int row = br + rep * 16;
            int c   = bq * 4;
            float4 val = make_float4(0.f, 0.f, 0.f, 0.f);
            if (row < krem && c < F) {
                val = *reinterpret_cast<const float4*>(W + (long)(k0 + row) * F + c);
            }
            *reinterpret_cast<float4*>(&ws[row][c]) = val;
        }

        __syncthreads();

#pragma unroll 8
        for (int kk = 0; kk < BK; ++kk) {
            float4 a0 = *reinterpret_cast<const float4*>(&xst[kk][rm]);
            float4 a1 = *reinterpret_cast<const float4*>(&xst[kk][rm + 4]);
            float4 bv = *reinterpret_cast<const float4*>(&ws[kk][cn]);
            float av[8] = {a0.x, a0.y, a0.z, a0.w, a1.x, a1.y, a1.z, a1.w};
            float bb[4] = {bv.x, bv.y, bv.z, bv.w};
#pragma unroll
            for (int i = 0; i < 8; ++i)
#pragma unroll
                for (int j = 0; j < 4; ++j)
                    acc[i][j] += av[i] * bb[j];
        }

        __syncthreads();
    }

    if (cn < F) {
#pragma unroll
        for (int i = 0; i < 8; ++i) {
            int grow = brow + rm + i;
            if (grow >= N_NODES) continue;
            *reinterpret_cast<float4*>(h + (long)grow * F + cn) =
                make_float4(acc[i][0], acc[i][1], acc[i][2], acc[i][3]);
        }
    }
}

// ---------------- pull aggregation + bias + BN + ReLU ----------------
template <int F>
__global__ __launch_bounds__(256) void k_agg_bn_relu(
        const float* __restrict__ h, const int* __restrict__ rowptr,
        const int* __restrict__ degi, const int* __restrict__ col,
        const float* __restrict__ valn, const float* __restrict__ dis,
        const float* __restrict__ bias, const float* __restrict__ g,
        const float* __restrict__ be, const float* __restrict__ m,
        const float* __restrict__ v, float* __restrict__ out) {
    int wid  = (blockIdx.x * 256 + threadIdx.x) >> 6;
    int lane = threadIdx.x & 63;
    if (wid >= N_NODES) return;

    int start = rowptr[wid];
    int cnt   = degi[wid];

    float acc = 0.0f;
    if (lane < F) {
        float d = dis[wid];
        acc = h[(long)wid * F + lane] * d * d + bias[lane];
    }

    int j = 0;
    for (; j + 4 <= cnt; j += 4) {
        int   s0 = col[start + j + 0], s1 = col[start + j + 1];
        int   s2 = col[start + j + 2], s3 = col[start + j + 3];
        float w0 = valn[start + j + 0], w1 = valn[start + j + 1];
        float w2 = valn[start + j + 2], w3 = valn[start + j + 3];
        if (lane < F) {
            float h0 = h[(long)s0 * F + lane];
            float h1 = h[(long)s1 * F + lane];
            float h2 = h[(long)s2 * F + lane];
            float h3 = h[(long)s3 * F + lane];
            acc += h0 * w0; acc += h1 * w1; acc += h2 * w2; acc += h3 * w3;
        }
    }
    for (; j < cnt; ++j) {
        int   s = col[start + j];
        float w = valn[start + j];
        if (lane < F) acc += h[(long)s * F + lane] * w;
    }

    if (lane < F) {
        float xv = (acc - m[lane]) * rsqrtf(v[lane] + BN_EPS) * g[lane] + be[lane];
        out[(long)wid * F + lane] = fmaxf(xv, 0.0f);
    }
}

// ---------------- pull aggregation + bias + log_softmax (layer 3) ----------------
template <int F>
__global__ __launch_bounds__(256) void k_agg_lsm(
        const float* __restrict__ h, const int* __restrict__ rowptr,
        const int* __restrict__ degi, const int* __restrict__ col,
        const float* __restrict__ valn, const float* __restrict__ dis,
        const float* __restrict__ bias, float* __restrict__ out) {
    int wid  = (blockIdx.x * 256 + threadIdx.x) >> 6;
    int lane = threadIdx.x & 63;
    if (wid >= N_NODES) return;

    int start = rowptr[wid];
    int cnt   = degi[wid];

    float acc = 0.0f;
    if (lane < F) {
        float d = dis[wid];
        acc = h[(long)wid * F + lane] * d * d + bias[lane];
    }

    int j = 0;
    for (; j + 4 <= cnt; j += 4) {
        int   s0 = col[start + j + 0], s1 = col[start + j + 1];
        int   s2 = col[start + j + 2], s3 = col[start + j + 3];
        float w0 = valn[start + j + 0], w1 = valn[start + j + 1];
        float w2 = valn[start + j + 2], w3 = valn[start + j + 3];
        if (lane < F) {
            float h0 = h[(long)s0 * F + lane];
            float h1 = h[(long)s1 * F + lane];
            float h2 = h[(long)s2 * F + lane];
            float h3 = h[(long)s3 * F + lane];
            acc += h0 * w0; acc += h1 * w1; acc += h2 * w2; acc += h3 * w3;
        }
    }
    for (; j < cnt; ++j) {
        int   s = col[start + j];
        float w = valn[start + j];
        if (lane < F) acc += h[(long)s * F + lane] * w;
    }

    float valf = (lane < F) ? acc : -INFINITY;
    float mx = valf;
#pragma unroll
    for (int o = 32; o > 0; o >>= 1) mx = fmaxf(mx, __shfl_xor(mx, o));
    float ex = (lane < F) ? expf(valf - mx) : 0.0f;
    float sm = ex;
#pragma unroll
    for (int o = 32; o > 0; o >>= 1) sm += __shfl_xor(sm, o);
    float ls = logf(sm);
    if (lane < F) out[(long)wid * F + lane] = valf - mx - ls;
}

extern "C" void kernel_launch(void* const* d_in, const int* in_sizes, int n_in,
                              void* d_out, int out_size, void* d_ws, size_t ws_size,
                              hipStream_t stream) {
    const float* x   = (const float*)d_in[0];
    const int*   ei  = (const int*)d_in[1];
    const float* W1  = (const float*)d_in[2];
    const float* b1  = (const float*)d_in[3];
    const float* g1  = (const float*)d_in[4];
    const float* be1 = (const float*)d_in[5];
    const float* m1  = (const float*)d_in[6];
    const float* v1  = (const float*)d_in[7];
    const float* W2  = (const float*)d_in[8];
    const float* b2  = (const float*)d_in[9];
    const float* g2  = (const float*)d_in[10];
    const float* be2 = (const float*)d_in[11];
    const float* m2  = (const float*)d_in[12];
    const float* v2  = (const float*)d_in[13];
    const float* W3  = (const float*)d_in[14];
    const float* b3  = (const float*)d_in[15];
    float* out = (float*)d_out;

    // workspace layout (all 16B-aligned)
    float* ws        = (float*)d_ws;
    float* dis       = ws;                            // 100096
    int*   degi      = (int*)(ws + 100096);           // 100096
    int*   cursor    = degi + 100096;                 // 100096
    int*   rowptr    = cursor + 100096;               // 100096
    int*   blocksum  = rowptr + 100096;               // 128
    int*   blockbase = blocksum + 128;                // 128
    int*   col       = blockbase + 128;               // 1.6M
    float* valn      = (float*)(col + N_EDGES);       // 1.6M
    float* bufH      = valn + N_EDGES;                // 6.4M
    float* bufA      = bufH + (long)N_NODES * HID;    // 6.4M

    // ---- CSR build ----
    k_zero2<<<cdiv(N_NODES, 256), 256, 0, stream>>>(degi, cursor);
    k_count_deg<<<cdiv(N_EDGES, 256), 256, 0, stream>>>(ei, degi);
    k_dis<<<cdiv(N_NODES, 256), 256, 0, stream>>>(degi, dis);
    k_scan1<<<SCAN_NB, 256, 0, stream>>>(degi, rowptr, blocksum);
    k_scan2<<<1, 128, 0, stream>>>(blocksum, blockbase);
    k_scan3<<<SCAN_NB, 256, 0, stream>>>(rowptr, blockbase);
    k_permute<<<cdiv(N_EDGES, 256), 256, 0, stream>>>(ei, rowptr, cursor, dis, col, valn);

    const int gemm_grid = cdiv(N_NODES, 128);
    const int agg_grid  = cdiv((long)N_NODES * 64, 256);

    // ---- layer 1: 500 -> 64 ----
    k_gemm<IN_DIM, HID><<<gemm_grid, 256, 0, stream>>>(x, W1, bufH);
    k_agg_bn_relu<HID><<<agg_grid, 256, 0, stream>>>(bufH, rowptr, degi, col, valn,
                                                     dis, b1, g1, be1, m1, v1, bufA);

    // ---- layer 2: 64 -> 64 ----
    k_gemm<HID, HID><<<gemm_grid, 256, 0, stream>>>(bufA, W2, bufH);
    k_agg_bn_relu<HID><<<agg_grid, 256, 0, stream>>>(bufH, rowptr, degi, col, valn,
                                                     dis, b2, g2, be2, m2, v2, bufA);

    // ---- layer 3: 64 -> 40 ----
    k_gemm<HID, OUT_DIM><<<gemm_grid, 256, 0, stream>>>(bufA, W3, bufH);
    k_agg_lsm<OUT_DIM><<<agg_grid, 256, 0, stream>>>(bufH, rowptr, degi, col, valn,
                                                     dis, b3, out);
}

// Round 5
// 546.284 us; speedup vs baseline: 3.8266x; 1.0171x over previous
//
#include <hip/hip_runtime.h>
#include <math.h>

#define N_NODES 100000
#define N_EDGES 1600000
#define IN_DIM  500
#define HID     64
#define OUT_DIM 40
#define BN_EPS  1e-5f
#define SCAN_NB 98          // ceil(100000 / 1024)

typedef __attribute__((ext_vector_type(8))) short bf16x8;
typedef __attribute__((ext_vector_type(4))) float f32x4;
typedef __attribute__((ext_vector_type(4))) unsigned short u16x4;

static inline int cdiv(long a, int b) { return (int)((a + b - 1) / b); }

__device__ inline unsigned short f2bf_rne(float f) {
    unsigned int u = __float_as_uint(f);
    unsigned int r = (u + 0x7FFFu + ((u >> 16) & 1u)) >> 16;
    return (unsigned short)r;
}
__device__ inline float bf2f(unsigned short h) {
    return __uint_as_float(((unsigned int)h) << 16);
}

// ---------------- zero int scratch ----------------
__global__ void k_zero2(int* a, int* b) {
    int i = blockIdx.x * 256 + threadIdx.x;
    if (i < N_NODES) { a[i] = 0; b[i] = 0; }
}

// ---------------- integer in-degree ----------------
__global__ void k_count_deg(const int* __restrict__ ei, int* degi) {
    int e = blockIdx.x * 256 + threadIdx.x;
    if (e < N_EDGES) atomicAdd(&degi[ei[N_EDGES + e]], 1);
}

__global__ void k_dis(const int* __restrict__ degi, float* dis) {
    int i = blockIdx.x * 256 + threadIdx.x;
    if (i < N_NODES) dis[i] = rsqrtf((float)degi[i] + 1.0f);
}

// ---------------- exclusive scan (3 kernels) ----------------
__global__ void k_scan1(const int* __restrict__ degi, int* __restrict__ rowptr,
                        int* __restrict__ blocksum) {
    __shared__ int sd[256];
    int tid = threadIdx.x;
    int base = blockIdx.x * 1024 + tid * 4;
    int v0 = (base + 0 < N_NODES) ? degi[base + 0] : 0;
    int v1 = (base + 1 < N_NODES) ? degi[base + 1] : 0;
    int v2 = (base + 2 < N_NODES) ? degi[base + 2] : 0;
    int v3 = (base + 3 < N_NODES) ? degi[base + 3] : 0;
    int s = v0 + v1 + v2 + v3;
    sd[tid] = s;
    __syncthreads();
    for (int off = 1; off < 256; off <<= 1) {
        int t = (tid >= off) ? sd[tid - off] : 0;
        __syncthreads();
        sd[tid] += t;
        __syncthreads();
    }
    int excl = sd[tid] - s;
    if (base + 0 < N_NODES) rowptr[base + 0] = excl;
    if (base + 1 < N_NODES) rowptr[base + 1] = excl + v0;
    if (base + 2 < N_NODES) rowptr[base + 2] = excl + v0 + v1;
    if (base + 3 < N_NODES) rowptr[base + 3] = excl + v0 + v1 + v2;
    if (tid == 255) blocksum[blockIdx.x] = sd[255];
}

__global__ void k_scan2(int* __restrict__ blocksum, int* __restrict__ blockbase) {
    __shared__ int sd[128];
    int tid = threadIdx.x;
    int v = (tid < SCAN_NB) ? blocksum[tid] : 0;
    sd[tid] = v;
    __syncthreads();
    for (int off = 1; off < 128; off <<= 1) {
        int t = (tid >= off) ? sd[tid - off] : 0;
        __syncthreads();
        sd[tid] += t;
        __syncthreads();
    }
    if (tid < SCAN_NB) blockbase[tid] = sd[tid] - v;
}

__global__ void k_scan3(int* __restrict__ rowptr, const int* __restrict__ blockbase) {
    int add = blockbase[blockIdx.x];
    int base = blockIdx.x * 1024 + threadIdx.x * 4;
#pragma unroll
    for (int i = 0; i < 4; ++i)
        if (base + i < N_NODES) rowptr[base + i] += add;
}

// ---------------- CSR permute: group edges by dst ----------------
__global__ void k_permute(const int* __restrict__ ei, const int* __restrict__ rowptr,
                          int* __restrict__ cursor, const float* __restrict__ dis,
                          int* __restrict__ col, float* __restrict__ valn) {
    int e = blockIdx.x * 256 + threadIdx.x;
    if (e >= N_EDGES) return;
    int s = ei[e];
    int d = ei[N_EDGES + e];
    int pos = rowptr[d] + atomicAdd(&cursor[d], 1);
    col[pos]  = s;
    valn[pos] = dis[s] * dis[d];
}

// ---------------- weight preconvert: W[K,F] -> Wt_hi/lo[64][KP] (transposed,
// zero-padded in both k (K..KP) and n (F..64)) ----------------
template <int K, int F, int KP>
__global__ void k_convW(const float* __restrict__ W,
                        unsigned short* __restrict__ wt_hi,
                        unsigned short* __restrict__ wt_lo) {
    int idx = blockIdx.x * 256 + threadIdx.x;
    if (idx >= 64 * KP) return;
    int n = idx / KP, k = idx % KP;
    float v = (n < F && k < K) ? W[(long)k * F + n] : 0.f;
    unsigned short hi = f2bf_rne(v);
    unsigned short lo = f2bf_rne(v - bf2f(hi));
    wt_hi[idx] = hi;
    wt_lo[idx] = lo;
}

// ---------------- split-bf16 MFMA GEMM: h[N,F] = x[N,K] @ W[K,F] ----------------
// BM=128, BK=64, 4 waves (2x2), wave-tile 64x32, mfma_f32_16x16x32_bf16.
// C = Ah*Bh + Ah*Bl + Al*Bh  (Al*Bl dropped, ~2^-16 relative)
template <int K, int KP, int F>
__global__ __launch_bounds__(256) void k_gemm_mfma(
        const float* __restrict__ x,
        const unsigned short* __restrict__ wt_hi,
        const unsigned short* __restrict__ wt_lo,
        float* __restrict__ h) {
    constexpr int BM = 128, BK = 64;
    constexpr int AS = 72;   // lds row stride (bf16 elems): 144 B -> bank-group shift 1
    __shared__ unsigned short Ah[BM][AS], Al[BM][AS];
    __shared__ unsigned short Bh[64][AS],  Bl[64][AS];

    const int tid   = threadIdx.x;
    const int wid   = tid >> 6;
    const int lane  = tid & 63;
    const int brow  = blockIdx.x * BM;
    const int mbase = (wid >> 1) * 64;   // 0 / 64
    const int nbase = (wid & 1) * 32;    // 0 / 32
    const int l15   = lane & 15;
    const int lhi   = lane >> 4;

    f32x4 acc[4][2];
#pragma unroll
    for (int mt = 0; mt < 4; ++mt)
#pragma unroll
        for (int nt = 0; nt < 2; ++nt)
            acc[mt][nt] = (f32x4){0.f, 0.f, 0.f, 0.f};

    for (int k0 = 0; k0 < KP; k0 += BK) {
        // ---- stage A: fp32 -> (hi,lo) bf16, 128 rows x 64 k ----
#pragma unroll
        for (int p = 0; p < 8; ++p) {
            int row  = p * 16 + (tid >> 4);
            int grow = brow + row;
            int c    = (tid & 15) * 4;
            int gk   = k0 + c;
            float4 v = make_float4(0.f, 0.f, 0.f, 0.f);
            if (grow < N_NODES) {
                const float* xp = x + (long)grow * K + gk;
                if (gk + 4 <= K) {
                    v = *reinterpret_cast<const float4*>(xp);
                } else {
                    if (gk + 0 < K) v.x = xp[0];
                    if (gk + 1 < K) v.y = xp[1];
                    if (gk + 2 < K) v.z = xp[2];
                    if (gk + 3 < K) v.w = xp[3];
                }
            }
            float vv[4] = {v.x, v.y, v.z, v.w};
            u16x4 hi4, lo4;
#pragma unroll
            for (int i = 0; i < 4; ++i) {
                unsigned short h16 = f2bf_rne(vv[i]);
                hi4[i] = h16;
                lo4[i] = f2bf_rne(vv[i] - bf2f(h16));
            }
            *reinterpret_cast<u16x4*>(&Ah[row][c]) = hi4;
            *reinterpret_cast<u16x4*>(&Al[row][c]) = lo4;
        }

        // ---- stage B: bf16 copy of pre-transposed weights ----
#pragma unroll
        for (int p = 0; p < 2; ++p) {
            int n = p * 32 + (tid >> 3);
            int c = (tid & 7) * 8;
            *reinterpret_cast<bf16x8*>(&Bh[n][c]) =
                *reinterpret_cast<const bf16x8*>(wt_hi + (long)n * KP + k0 + c);
            *reinterpret_cast<bf16x8*>(&Bl[n][c]) =
                *reinterpret_cast<const bf16x8*>(wt_lo + (long)n * KP + k0 + c);
        }

        __syncthreads();

#pragma unroll
        for (int s = 0; s < 2; ++s) {
            const int kk = s * 32 + lhi * 8;
            bf16x8 ah[4], al[4], bh[2], bl[2];
#pragma unroll
            for (int mt = 0; mt < 4; ++mt) {
                int r = mbase + mt * 16 + l15;
                ah[mt] = *reinterpret_cast<const bf16x8*>(&Ah[r][kk]);
                al[mt] = *reinterpret_cast<const bf16x8*>(&Al[r][kk]);
            }
#pragma unroll
            for (int nt = 0; nt < 2; ++nt) {
                int r = nbase + nt * 16 + l15;
                bh[nt] = *reinterpret_cast<const bf16x8*>(&Bh[r][kk]);
                bl[nt] = *reinterpret_cast<const bf16x8*>(&Bl[r][kk]);
            }
#pragma unroll
            for (int mt = 0; mt < 4; ++mt)
#pragma unroll
                for (int nt = 0; nt < 2; ++nt) {
                    acc[mt][nt] = __builtin_amdgcn_mfma_f32_16x16x32_bf16(
                        al[mt], bh[nt], acc[mt][nt], 0, 0, 0);
                    acc[mt][nt] = __builtin_amdgcn_mfma_f32_16x16x32_bf16(
                        ah[mt], bl[nt], acc[mt][nt], 0, 0, 0);
                    acc[mt][nt] = __builtin_amdgcn_mfma_f32_16x16x32_bf16(
                        ah[mt], bh[nt], acc[mt][nt], 0, 0, 0);
                }
        }

        __syncthreads();
    }

    // epilogue: C/D layout (verified): col = lane&15, row = (lane>>4)*4 + reg
    const int crow = lhi * 4;
#pragma unroll
    for (int mt = 0; mt < 4; ++mt)
#pragma unroll
        for (int nt = 0; nt < 2; ++nt) {
            int coln = nbase + nt * 16 + l15;
            if (F != 64 && coln >= F) continue;
#pragma unroll
            for (int r = 0; r < 4; ++r) {
                int grow = brow + mbase + mt * 16 + crow + r;
                if (grow < N_NODES)
                    h[(long)grow * F + coln] = acc[mt][nt][r];
            }
        }
}

// ---------------- pull aggregation + bias + BN + ReLU ----------------
template <int F>
__global__ __launch_bounds__(256) void k_agg_bn_relu(
        const float* __restrict__ h, const int* __restrict__ rowptr,
        const int* __restrict__ degi, const int* __restrict__ col,
        const float* __restrict__ valn, const float* __restrict__ dis,
        const float* __restrict__ bias, const float* __restrict__ g,
        const float* __restrict__ be, const float* __restrict__ m,
        const float* __restrict__ v, float* __restrict__ out) {
    int wid  = (blockIdx.x * 256 + threadIdx.x) >> 6;
    int lane = threadIdx.x & 63;
    if (wid >= N_NODES) return;

    int start = rowptr[wid];
    int cnt   = degi[wid];

    float acc = 0.0f;
    if (lane < F) {
        float d = dis[wid];
        acc = h[(long)wid * F + lane] * d * d + bias[lane];
    }

    int j = 0;
    for (; j + 4 <= cnt; j += 4) {
        int   s0 = col[start + j + 0], s1 = col[start + j + 1];
        int   s2 = col[start + j + 2], s3 = col[start + j + 3];
        float w0 = valn[start + j + 0], w1 = valn[start + j + 1];
        float w2 = valn[start + j + 2], w3 = valn[start + j + 3];
        if (lane < F) {
            float h0 = h[(long)s0 * F + lane];
            float h1 = h[(long)s1 * F + lane];
            float h2 = h[(long)s2 * F + lane];
            float h3 = h[(long)s3 * F + lane];
            acc += h0 * w0; acc += h1 * w1; acc += h2 * w2; acc += h3 * w3;
        }
    }
    for (; j < cnt; ++j) {
        int   s = col[start + j];
        float w = valn[start + j];
        if (lane < F) acc += h[(long)s * F + lane] * w;
    }

    if (lane < F) {
        float xv = (acc - m[lane]) * rsqrtf(v[lane] + BN_EPS) * g[lane] + be[lane];
        out[(long)wid * F + lane] = fmaxf(xv, 0.0f);
    }
}

// ---------------- pull aggregation + bias + log_softmax (layer 3) ----------------
template <int F>
__global__ __launch_bounds__(256) void k_agg_lsm(
        const float* __restrict__ h, const int* __restrict__ rowptr,
        const int* __restrict__ degi, const int* __restrict__ col,
        const float* __restrict__ valn, const float* __restrict__ dis,
        const float* __restrict__ bias, float* __restrict__ out) {
    int wid  = (blockIdx.x * 256 + threadIdx.x) >> 6;
    int lane = threadIdx.x & 63;
    if (wid >= N_NODES) return;

    int start = rowptr[wid];
    int cnt   = degi[wid];

    float acc = 0.0f;
    if (lane < F) {
        float d = dis[wid];
        acc = h[(long)wid * F + lane] * d * d + bias[lane];
    }

    int j = 0;
    for (; j + 4 <= cnt; j += 4) {
        int   s0 = col[start + j + 0], s1 = col[start + j + 1];
        int   s2 = col[start + j + 2], s3 = col[start + j + 3];
        float w0 = valn[start + j + 0], w1 = valn[start + j + 1];
        float w2 = valn[start + j + 2], w3 = valn[start + j + 3];
        if (lane < F) {
            float h0 = h[(long)s0 * F + lane];
            float h1 = h[(long)s1 * F + lane];
            float h2 = h[(long)s2 * F + lane];
            float h3 = h[(long)s3 * F + lane];
            acc += h0 * w0; acc += h1 * w1; acc += h2 * w2; acc += h3 * w3;
        }
    }
    for (; j < cnt; ++j) {
        int   s = col[start + j];
        float w = valn[start + j];
        if (lane < F) acc += h[(long)s * F + lane] * w;
    }

    float valf = (lane < F) ? acc : -INFINITY;
    float mx = valf;
#pragma unroll
    for (int o = 32; o > 0; o >>= 1) mx = fmaxf(mx, __shfl_xor(mx, o));
    float ex = (lane < F) ? expf(valf - mx) : 0.0f;
    float sm = ex;
#pragma unroll
    for (int o = 32; o > 0; o >>= 1) sm += __shfl_xor(sm, o);
    float ls = logf(sm);
    if (lane < F) out[(long)wid * F + lane] = valf - mx - ls;
}

extern "C" void kernel_launch(void* const* d_in, const int* in_sizes, int n_in,
                              void* d_out, int out_size, void* d_ws, size_t ws_size,
                              hipStream_t stream) {
    const float* x   = (const float*)d_in[0];
    const int*   ei  = (const int*)d_in[1];
    const float* W1  = (const float*)d_in[2];
    const float* b1  = (const float*)d_in[3];
    const float* g1  = (const float*)d_in[4];
    const float* be1 = (const float*)d_in[5];
    const float* m1  = (const float*)d_in[6];
    const float* v1  = (const float*)d_in[7];
    const float* W2  = (const float*)d_in[8];
    const float* b2  = (const float*)d_in[9];
    const float* g2  = (const float*)d_in[10];
    const float* be2 = (const float*)d_in[11];
    const float* m2  = (const float*)d_in[12];
    const float* v2  = (const float*)d_in[13];
    const float* W3  = (const float*)d_in[14];
    const float* b3  = (const float*)d_in[15];
    float* out = (float*)d_out;

    // workspace layout (16B-aligned slabs)
    float* ws        = (float*)d_ws;
    float* dis       = ws;                            // 100096
    int*   degi      = (int*)(ws + 100096);           // 100096
    int*   cursor    = degi + 100096;                 // 100096
    int*   rowptr    = cursor + 100096;               // 100096
    int*   blocksum  = rowptr + 100096;               // 128
    int*   blockbase = blocksum + 128;                // 128
    int*   col       = blockbase + 128;               // 1.6M
    float* valn      = (float*)(col + N_EDGES);       // 1.6M
    float* bufH      = valn + N_EDGES;                // 6.4M
    float* bufA      = bufH + (long)N_NODES * HID;    // 6.4M
    unsigned short* wt1_hi = (unsigned short*)(bufA + (long)N_NODES * HID); // 64*512
    unsigned short* wt1_lo = wt1_hi + 64 * 512;
    unsigned short* wt2_hi = wt1_lo + 64 * 512;       // 64*64
    unsigned short* wt2_lo = wt2_hi + 64 * 64;
    unsigned short* wt3_hi = wt2_lo + 64 * 64;        // 64*64
    unsigned short* wt3_lo = wt3_hi + 64 * 64;

    // ---- CSR build ----
    k_zero2<<<cdiv(N_NODES, 256), 256, 0, stream>>>(degi, cursor);
    k_count_deg<<<cdiv(N_EDGES, 256), 256, 0, stream>>>(ei, degi);
    k_dis<<<cdiv(N_NODES, 256), 256, 0, stream>>>(degi, dis);
    k_scan1<<<SCAN_NB, 256, 0, stream>>>(degi, rowptr, blocksum);
    k_scan2<<<1, 128, 0, stream>>>(blocksum, blockbase);
    k_scan3<<<SCAN_NB, 256, 0, stream>>>(rowptr, blockbase);
    k_permute<<<cdiv(N_EDGES, 256), 256, 0, stream>>>(ei, rowptr, cursor, dis, col, valn);

    // ---- weight preconvert (hi/lo bf16, transposed, zero-padded) ----
    k_convW<IN_DIM, HID, 512><<<(64 * 512) / 256, 256, 0, stream>>>(W1, wt1_hi, wt1_lo);
    k_convW<HID, HID, 64><<<(64 * 64) / 256, 256, 0, stream>>>(W2, wt2_hi, wt2_lo);
    k_convW<HID, OUT_DIM, 64><<<(64 * 64) / 256, 256, 0, stream>>>(W3, wt3_hi, wt3_lo);

    const int gemm_grid = cdiv(N_NODES, 128);
    const int agg_grid  = cdiv((long)N_NODES * 64, 256);

    // ---- layer 1: 500 -> 64 ----
    k_gemm_mfma<IN_DIM, 512, HID><<<gemm_grid, 256, 0, stream>>>(x, wt1_hi, wt1_lo, bufH);
    k_agg_bn_relu<HID><<<agg_grid, 256, 0, stream>>>(bufH, rowptr, degi, col, valn,
                                                     dis, b1, g1, be1, m1, v1, bufA);

    // ---- layer 2: 64 -> 64 ----
    k_gemm_mfma<HID, 64, HID><<<gemm_grid, 256, 0, stream>>>(bufA, wt2_hi, wt2_lo, bufH);
    k_agg_bn_relu<HID><<<agg_grid, 256, 0, stream>>>(bufH, rowptr, degi, col, valn,
                                                     dis, b2, g2, be2, m2, v2, bufA);

    // ---- layer 3: 64 -> 40 ----
    k_gemm_mfma<HID, 64, OUT_DIM><<<gemm_grid, 256, 0, stream>>>(bufA, wt3_hi, wt3_lo, bufH);
    k_agg_lsm<OUT_DIM><<<agg_grid, 256, 0, stream>>>(bufH, rowptr, degi, col, valn,
                                                     dis, b3, out);
}

// Round 6
// 523.988 us; speedup vs baseline: 3.9894x; 1.0426x over previous
//
#include <hip/hip_runtime.h>
#include <math.h>

#define N_NODES 100000
#define N_EDGES 1600000
#define IN_DIM  500
#define HID     64
#define OUT_DIM 40
#define BN_EPS  1e-5f
#define SCAN_NB 98          // ceil(100000 / 1024)

typedef __attribute__((ext_vector_type(8))) short bf16x8;
typedef __attribute__((ext_vector_type(4))) float f32x4;

static inline int cdiv(long a, int b) { return (int)((a + b - 1) / b); }

__device__ inline unsigned short f2bf_rne(float f) {
    unsigned int u = __float_as_uint(f);
    unsigned int r = (u + 0x7FFFu + ((u >> 16) & 1u)) >> 16;
    return (unsigned short)r;
}
__device__ inline float bf2f(unsigned short h) {
    return __uint_as_float(((unsigned int)h) << 16);
}

// ---------------- zero int scratch ----------------
__global__ void k_zero2(int* a, int* b) {
    int i = blockIdx.x * 256 + threadIdx.x;
    if (i < N_NODES) { a[i] = 0; b[i] = 0; }
}

// ---------------- integer in-degree ----------------
__global__ void k_count_deg(const int* __restrict__ ei, int* degi) {
    int e = blockIdx.x * 256 + threadIdx.x;
    if (e < N_EDGES) atomicAdd(&degi[ei[N_EDGES + e]], 1);
}

__global__ void k_dis(const int* __restrict__ degi, float* dis) {
    int i = blockIdx.x * 256 + threadIdx.x;
    if (i < N_NODES) dis[i] = rsqrtf((float)degi[i] + 1.0f);
}

// ---------------- exclusive scan (3 kernels) ----------------
__global__ void k_scan1(const int* __restrict__ degi, int* __restrict__ rowptr,
                        int* __restrict__ blocksum) {
    __shared__ int sd[256];
    int tid = threadIdx.x;
    int base = blockIdx.x * 1024 + tid * 4;
    int v0 = (base + 0 < N_NODES) ? degi[base + 0] : 0;
    int v1 = (base + 1 < N_NODES) ? degi[base + 1] : 0;
    int v2 = (base + 2 < N_NODES) ? degi[base + 2] : 0;
    int v3 = (base + 3 < N_NODES) ? degi[base + 3] : 0;
    int s = v0 + v1 + v2 + v3;
    sd[tid] = s;
    __syncthreads();
    for (int off = 1; off < 256; off <<= 1) {
        int t = (tid >= off) ? sd[tid - off] : 0;
        __syncthreads();
        sd[tid] += t;
        __syncthreads();
    }
    int excl = sd[tid] - s;
    if (base + 0 < N_NODES) rowptr[base + 0] = excl;
    if (base + 1 < N_NODES) rowptr[base + 1] = excl + v0;
    if (base + 2 < N_NODES) rowptr[base + 2] = excl + v0 + v1;
    if (base + 3 < N_NODES) rowptr[base + 3] = excl + v0 + v1 + v2;
    if (tid == 255) blocksum[blockIdx.x] = sd[255];
}

__global__ void k_scan2(int* __restrict__ blocksum, int* __restrict__ blockbase) {
    __shared__ int sd[128];
    int tid = threadIdx.x;
    int v = (tid < SCAN_NB) ? blocksum[tid] : 0;
    sd[tid] = v;
    __syncthreads();
    for (int off = 1; off < 128; off <<= 1) {
        int t = (tid >= off) ? sd[tid - off] : 0;
        __syncthreads();
        sd[tid] += t;
        __syncthreads();
    }
    if (tid < SCAN_NB) blockbase[tid] = sd[tid] - v;
}

__global__ void k_scan3(int* __restrict__ rowptr, const int* __restrict__ blockbase) {
    int add = blockbase[blockIdx.x];
    int base = blockIdx.x * 1024 + threadIdx.x * 4;
#pragma unroll
    for (int i = 0; i < 4; ++i)
        if (base + i < N_NODES) rowptr[base + i] += add;
}

// ---------------- CSR permute: group edges by dst ----------------
__global__ void k_permute(const int* __restrict__ ei, const int* __restrict__ rowptr,
                          int* __restrict__ cursor, const float* __restrict__ dis,
                          int* __restrict__ col, float* __restrict__ valn) {
    int e = blockIdx.x * 256 + threadIdx.x;
    if (e >= N_EDGES) return;
    int s = ei[e];
    int d = ei[N_EDGES + e];
    int pos = rowptr[d] + atomicAdd(&cursor[d], 1);
    col[pos]  = s;
    valn[pos] = dis[s] * dis[d];
}

// ---------------- weight preconvert: W[K,F] -> Wt_hi/lo[64][KP] (transposed,
// zero-padded in k (K..KP) and n (F..64)) ----------------
template <int K, int F, int KP>
__global__ void k_convW(const float* __restrict__ W,
                        unsigned short* __restrict__ wt_hi,
                        unsigned short* __restrict__ wt_lo) {
    int idx = blockIdx.x * 256 + threadIdx.x;
    if (idx >= 64 * KP) return;
    int n = idx / KP, k = idx % KP;
    float v = (n < F && k < K) ? W[(long)k * F + n] : 0.f;
    unsigned short hi = f2bf_rne(v);
    unsigned short lo = f2bf_rne(v - bf2f(hi));
    wt_hi[idx] = hi;
    wt_lo[idx] = lo;
}

// ---------------- split-bf16 MFMA GEMM, m97-style staging ----------------
// h[N,F] = x[N,K] @ W[K,F].  BM=64, BK=64, 4 waves (2x2), wave-tile 32x32.
// A staged as RAW FP32 via global_load_lds (16 KB, linear); hi/lo bf16 split
// happens at fragment read. B fragments come straight from L2 (pre-transposed,
// zero-padded weights) - no LDS, no barrier for B.
// C = Ah*Bh + Ah*Bl + Al*Bh.
template <int K, int KP, int F>
__global__ __launch_bounds__(256) void k_gemm_mfma(
        const float* __restrict__ x,
        const unsigned short* __restrict__ wt_hi,
        const unsigned short* __restrict__ wt_lo,
        float* __restrict__ h) {
    constexpr int BM = 64, BK = 64;
    constexpr int T  = KP / BK;
    __shared__ float As[BM * BK];     // linear [row][k], 256 B rows (global_load_lds dest)

    const int tid   = threadIdx.x;
    const int wid   = tid >> 6;
    const int lane  = tid & 63;
    const int l15   = lane & 15;
    const int lhi   = lane >> 4;
    const int brow  = blockIdx.x * BM;
    const int mbase = (wid >> 1) * 32;   // 0 / 32
    const int nbase = (wid & 1) * 32;    // 0 / 32

    const char* xb   = (const char*)x;
    const char* xend = xb + (long)N_NODES * K * 4 - 16;   // 16B-aligned clamp target

    f32x4 acc[2][2];
#pragma unroll
    for (int mt = 0; mt < 2; ++mt)
#pragma unroll
        for (int nt = 0; nt < 2; ++nt)
            acc[mt][nt] = (f32x4){0.f, 0.f, 0.f, 0.f};

    for (int t = 0; t < T; ++t) {
        const int k0 = t * BK;

        // ---- stage A tile: 64 rows x 64 fp32, direct global->LDS DMA ----
        // dest offset = tid*16 + p*4096 (linear; row = tid>>4 + p*16, unit = tid&15)
#pragma unroll
        for (int p = 0; p < 4; ++p) {
            long grow = brow + p * 16 + (tid >> 4);
            const char* src = xb + grow * (long)(K * 4) + (long)k0 * 4 + (tid & 15) * 16;
            if (src > xend) src = xend;   // row/k tail: garbage is masked by B zero-pad / store mask
            unsigned int* dst = (unsigned int*)((char*)As + p * 4096 + tid * 16);
            __builtin_amdgcn_global_load_lds((const unsigned int*)src, dst, 16, 0, 0);
        }
        __syncthreads();   // drains vmcnt -> tile ready

        // ---- compute on tile ----
#pragma unroll
        for (int s = 0; s < 2; ++s) {
            const int kk = s * 32 + lhi * 8;   // fp32 index within tile row

            // B fragments straight from global (L2-resident)
            bf16x8 bh[2], bl[2];
#pragma unroll
            for (int nt = 0; nt < 2; ++nt) {
                long off = (long)(nbase + nt * 16 + l15) * KP + k0 + kk;
                bh[nt] = *reinterpret_cast<const bf16x8*>(wt_hi + off);
                bl[nt] = *reinterpret_cast<const bf16x8*>(wt_lo + off);
            }

            // A fragments: fp32 from LDS, split to hi/lo bf16 in regs
            bf16x8 ah[2], al[2];
#pragma unroll
            for (int mt = 0; mt < 2; ++mt) {
                const float* ap = &As[(mbase + mt * 16 + l15) * BK + kk];
                f32x4 a0 = *reinterpret_cast<const f32x4*>(ap);
                f32x4 a1 = *reinterpret_cast<const f32x4*>(ap + 4);
                float av[8] = {a0[0], a0[1], a0[2], a0[3], a1[0], a1[1], a1[2], a1[3]};
#pragma unroll
                for (int i = 0; i < 8; ++i) {
                    unsigned short hi = f2bf_rne(av[i]);
                    ah[mt][i] = (short)hi;
                    al[mt][i] = (short)f2bf_rne(av[i] - bf2f(hi));
                }
            }

#pragma unroll
            for (int mt = 0; mt < 2; ++mt)
#pragma unroll
                for (int nt = 0; nt < 2; ++nt) {
                    acc[mt][nt] = __builtin_amdgcn_mfma_f32_16x16x32_bf16(
                        al[mt], bh[nt], acc[mt][nt], 0, 0, 0);
                    acc[mt][nt] = __builtin_amdgcn_mfma_f32_16x16x32_bf16(
                        ah[mt], bl[nt], acc[mt][nt], 0, 0, 0);
                    acc[mt][nt] = __builtin_amdgcn_mfma_f32_16x16x32_bf16(
                        ah[mt], bh[nt], acc[mt][nt], 0, 0, 0);
                }
        }
        __syncthreads();   // protect tile from next iteration's staging
    }

    // epilogue: C/D layout: col = lane&15, row = (lane>>4)*4 + reg
#pragma unroll
    for (int mt = 0; mt < 2; ++mt)
#pragma unroll
        for (int nt = 0; nt < 2; ++nt) {
            int coln = nbase + nt * 16 + l15;
            if (F != 64 && coln >= F) continue;
#pragma unroll
            for (int r = 0; r < 4; ++r) {
                int grow = brow + mbase + mt * 16 + lhi * 4 + r;
                if (grow < N_NODES)
                    h[(long)grow * F + coln] = acc[mt][nt][r];
            }
        }
}

// ---------------- pull aggregation + bias + BN + ReLU ----------------
template <int F>
__global__ __launch_bounds__(256) void k_agg_bn_relu(
        const float* __restrict__ h, const int* __restrict__ rowptr,
        const int* __restrict__ degi, const int* __restrict__ col,
        const float* __restrict__ valn, const float* __restrict__ dis,
        const float* __restrict__ bias, const float* __restrict__ g,
        const float* __restrict__ be, const float* __restrict__ m,
        const float* __restrict__ v, float* __restrict__ out) {
    int wid  = (blockIdx.x * 256 + threadIdx.x) >> 6;
    int lane = threadIdx.x & 63;
    if (wid >= N_NODES) return;

    int start = rowptr[wid];
    int cnt   = degi[wid];

    float acc = 0.0f;
    if (lane < F) {
        float d = dis[wid];
        acc = h[(long)wid * F + lane] * d * d + bias[lane];
    }

    int j = 0;
    for (; j + 4 <= cnt; j += 4) {
        int   s0 = col[start + j + 0], s1 = col[start + j + 1];
        int   s2 = col[start + j + 2], s3 = col[start + j + 3];
        float w0 = valn[start + j + 0], w1 = valn[start + j + 1];
        float w2 = valn[start + j + 2], w3 = valn[start + j + 3];
        if (lane < F) {
            float h0 = h[(long)s0 * F + lane];
            float h1 = h[(long)s1 * F + lane];
            float h2 = h[(long)s2 * F + lane];
            float h3 = h[(long)s3 * F + lane];
            acc += h0 * w0; acc += h1 * w1; acc += h2 * w2; acc += h3 * w3;
        }
    }
    for (; j < cnt; ++j) {
        int   s = col[start + j];
        float w = valn[start + j];
        if (lane < F) acc += h[(long)s * F + lane] * w;
    }

    if (lane < F) {
        float xv = (acc - m[lane]) * rsqrtf(v[lane] + BN_EPS) * g[lane] + be[lane];
        out[(long)wid * F + lane] = fmaxf(xv, 0.0f);
    }
}

// ---------------- pull aggregation + bias + log_softmax (layer 3) ----------------
template <int F>
__global__ __launch_bounds__(256) void k_agg_lsm(
        const float* __restrict__ h, const int* __restrict__ rowptr,
        const int* __restrict__ degi, const int* __restrict__ col,
        const float* __restrict__ valn, const float* __restrict__ dis,
        const float* __restrict__ bias, float* __restrict__ out) {
    int wid  = (blockIdx.x * 256 + threadIdx.x) >> 6;
    int lane = threadIdx.x & 63;
    if (wid >= N_NODES) return;

    int start = rowptr[wid];
    int cnt   = degi[wid];

    float acc = 0.0f;
    if (lane < F) {
        float d = dis[wid];
        acc = h[(long)wid * F + lane] * d * d + bias[lane];
    }

    int j = 0;
    for (; j + 4 <= cnt; j += 4) {
        int   s0 = col[start + j + 0], s1 = col[start + j + 1];
        int   s2 = col[start + j + 2], s3 = col[start + j + 3];
        float w0 = valn[start + j + 0], w1 = valn[start + j + 1];
        float w2 = valn[start + j + 2], w3 = valn[start + j + 3];
        if (lane < F) {
            float h0 = h[(long)s0 * F + lane];
            float h1 = h[(long)s1 * F + lane];
            float h2 = h[(long)s2 * F + lane];
            float h3 = h[(long)s3 * F + lane];
            acc += h0 * w0; acc += h1 * w1; acc += h2 * w2; acc += h3 * w3;
        }
    }
    for (; j < cnt; ++j) {
        int   s = col[start + j];
        float w = valn[start + j];
        if (lane < F) acc += h[(long)s * F + lane] * w;
    }

    float valf = (lane < F) ? acc : -INFINITY;
    float mx = valf;
#pragma unroll
    for (int o = 32; o > 0; o >>= 1) mx = fmaxf(mx, __shfl_xor(mx, o));
    float ex = (lane < F) ? expf(valf - mx) : 0.0f;
    float sm = ex;
#pragma unroll
    for (int o = 32; o > 0; o >>= 1) sm += __shfl_xor(sm, o);
    float ls = logf(sm);
    if (lane < F) out[(long)wid * F + lane] = valf - mx - ls;
}

extern "C" void kernel_launch(void* const* d_in, const int* in_sizes, int n_in,
                              void* d_out, int out_size, void* d_ws, size_t ws_size,
                              hipStream_t stream) {
    const float* x   = (const float*)d_in[0];
    const int*   ei  = (const int*)d_in[1];
    const float* W1  = (const float*)d_in[2];
    const float* b1  = (const float*)d_in[3];
    const float* g1  = (const float*)d_in[4];
    const float* be1 = (const float*)d_in[5];
    const float* m1  = (const float*)d_in[6];
    const float* v1  = (const float*)d_in[7];
    const float* W2  = (const float*)d_in[8];
    const float* b2  = (const float*)d_in[9];
    const float* g2  = (const float*)d_in[10];
    const float* be2 = (const float*)d_in[11];
    const float* m2  = (const float*)d_in[12];
    const float* v2  = (const float*)d_in[13];
    const float* W3  = (const float*)d_in[14];
    const float* b3  = (const float*)d_in[15];
    float* out = (float*)d_out;

    // workspace layout (16B-aligned slabs)
    float* ws        = (float*)d_ws;
    float* dis       = ws;                            // 100096
    int*   degi      = (int*)(ws + 100096);           // 100096
    int*   cursor    = degi + 100096;                 // 100096
    int*   rowptr    = cursor + 100096;               // 100096
    int*   blocksum  = rowptr + 100096;               // 128
    int*   blockbase = blocksum + 128;                // 128
    int*   col       = blockbase + 128;               // 1.6M
    float* valn      = (float*)(col + N_EDGES);       // 1.6M
    float* bufH      = valn + N_EDGES;                // 6.4M
    float* bufA      = bufH + (long)N_NODES * HID;    // 6.4M
    unsigned short* wt1_hi = (unsigned short*)(bufA + (long)N_NODES * HID); // 64*512
    unsigned short* wt1_lo = wt1_hi + 64 * 512;
    unsigned short* wt2_hi = wt1_lo + 64 * 512;       // 64*64
    unsigned short* wt2_lo = wt2_hi + 64 * 64;
    unsigned short* wt3_hi = wt2_lo + 64 * 64;        // 64*64
    unsigned short* wt3_lo = wt3_hi + 64 * 64;

    // ---- CSR build ----
    k_zero2<<<cdiv(N_NODES, 256), 256, 0, stream>>>(degi, cursor);
    k_count_deg<<<cdiv(N_EDGES, 256), 256, 0, stream>>>(ei, degi);
    k_dis<<<cdiv(N_NODES, 256), 256, 0, stream>>>(degi, dis);
    k_scan1<<<SCAN_NB, 256, 0, stream>>>(degi, rowptr, blocksum);
    k_scan2<<<1, 128, 0, stream>>>(blocksum, blockbase);
    k_scan3<<<SCAN_NB, 256, 0, stream>>>(rowptr, blockbase);
    k_permute<<<cdiv(N_EDGES, 256), 256, 0, stream>>>(ei, rowptr, cursor, dis, col, valn);

    // ---- weight preconvert (hi/lo bf16, transposed, zero-padded) ----
    k_convW<IN_DIM, HID, 512><<<(64 * 512) / 256, 256, 0, stream>>>(W1, wt1_hi, wt1_lo);
    k_convW<HID, HID, 64><<<(64 * 64) / 256, 256, 0, stream>>>(W2, wt2_hi, wt2_lo);
    k_convW<HID, OUT_DIM, 64><<<(64 * 64) / 256, 256, 0, stream>>>(W3, wt3_hi, wt3_lo);

    const int gemm_grid = cdiv(N_NODES, 64);
    const int agg_grid  = cdiv((long)N_NODES * 64, 256);

    // ---- layer 1: 500 -> 64 ----
    k_gemm_mfma<IN_DIM, 512, HID><<<gemm_grid, 256, 0, stream>>>(x, wt1_hi, wt1_lo, bufH);
    k_agg_bn_relu<HID><<<agg_grid, 256, 0, stream>>>(bufH, rowptr, degi, col, valn,
                                                     dis, b1, g1, be1, m1, v1, bufA);

    // ---- layer 2: 64 -> 64 ----
    k_gemm_mfma<HID, 64, HID><<<gemm_grid, 256, 0, stream>>>(bufA, wt2_hi, wt2_lo, bufH);
    k_agg_bn_relu<HID><<<agg_grid, 256, 0, stream>>>(bufH, rowptr, degi, col, valn,
                                                     dis, b2, g2, be2, m2, v2, bufA);

    // ---- layer 3: 64 -> 40 ----
    k_gemm_mfma<HID, 64, OUT_DIM><<<gemm_grid, 256, 0, stream>>>(bufA, wt3_hi, wt3_lo, bufH);
    k_agg_lsm<OUT_DIM><<<agg_grid, 256, 0, stream>>>(bufH, rowptr, degi, col, valn,
                                                     dis, b3, out);
}